// Round 1
// baseline (1262.767 us; speedup 1.0000x reference)
//
#include <hip/hip_runtime.h>

typedef _Float16 half2v __attribute__((ext_vector_type(2)));

#define T_LEN 1024
#define NBATCH 1024
#define HID 20

#if defined(__has_builtin)
#if __has_builtin(__builtin_amdgcn_fdot2)
#define HAVE_FDOT2 1
#endif
#endif

__device__ __forceinline__ float fdot2_(half2v a, half2v b, float c) {
#ifdef HAVE_FDOT2
    return __builtin_amdgcn_fdot2(a, b, c, false);
#else
    return c + (float)a[0] * (float)b[0] + (float)a[1] * (float)b[1];
#endif
}

__device__ __forceinline__ float sigmoid_f(float z) {
    return 1.0f / (1.0f + __expf(-z));
}

__device__ __forceinline__ float tanh_f(float z) {
    float zc = fminf(fmaxf(z, -15.0f), 15.0f);
    float e = __expf(2.0f * zc);
    return (e - 1.0f) / (e + 1.0f);
}

__device__ __forceinline__ half2v pack2(float a, float b) {
    half2v r;
    r[0] = (_Float16)a;
    r[1] = (_Float16)b;
    return r;
}

// Load 20 f16 values (one padded 24-half row, 16B-aligned) into 10 half2 regs.
__device__ __forceinline__ void load_h20(const _Float16* row, half2v hp[10]) {
    uint4 q0 = *(const uint4*)(row);        // halfs 0..7
    uint4 q1 = *(const uint4*)(row + 8);    // halfs 8..15
    uint2 q2 = *(const uint2*)(row + 16);   // halfs 16..19
    hp[0] = __builtin_bit_cast(half2v, q0.x);
    hp[1] = __builtin_bit_cast(half2v, q0.y);
    hp[2] = __builtin_bit_cast(half2v, q0.z);
    hp[3] = __builtin_bit_cast(half2v, q0.w);
    hp[4] = __builtin_bit_cast(half2v, q1.x);
    hp[5] = __builtin_bit_cast(half2v, q1.y);
    hp[6] = __builtin_bit_cast(half2v, q1.z);
    hp[7] = __builtin_bit_cast(half2v, q1.w);
    hp[8] = __builtin_bit_cast(half2v, q2.x);
    hp[9] = __builtin_bit_cast(half2v, q2.y);
}

// One wave (block of 64) per batch element.
// Lanes 0..19  : half 0, hidden j = lane      -> gates i(j)   [row j]     and g(j) [row 40+j]
// Lanes 20..39 : half 1, hidden j = lane-20   -> gates f(j)   [row 20+j]  and o(j) [row 60+j]
// Lanes 40..63 : idle (ride along; never write)
__global__ void __launch_bounds__(64) lstm3_fused(
    const float* __restrict__ x,
    const float* __restrict__ wih0, const float* __restrict__ whh0,
    const float* __restrict__ bih0, const float* __restrict__ bhh0,
    const float* __restrict__ wih1, const float* __restrict__ whh1,
    const float* __restrict__ bih1, const float* __restrict__ bhh1,
    const float* __restrict__ wih2, const float* __restrict__ whh2,
    const float* __restrict__ bih2, const float* __restrict__ bhh2,
    const float* __restrict__ fcw, const float* __restrict__ fcb,
    float* __restrict__ out)
{
    __shared__ __align__(16) _Float16 hbuf[3][24];  // per-layer h, padded to 48B rows
    __shared__ float ubuf[HID];                     // sigma(i)*tanh(g) exchange

    const int tid = threadIdx.x;
    const int b = blockIdx.x;

    // zero h state (h0 = c0 = 0 in the reference)
    for (int i = tid; i < 3 * 24; i += 64) ((_Float16*)hbuf)[i] = (_Float16)0.0f;
    __syncthreads();

    const bool active = tid < 2 * HID;
    const int j = tid % HID;
    const int half = tid / HID;  // 0 or 1 for active lanes

    const int r0 = (half == 0) ? j : (HID + j);          // i-gate or f-gate row
    const int r1 = (half == 0) ? (2 * HID + j) : (3 * HID + j);  // g-gate or o-gate row

    half2v Whh[2][3][10];   // [gate][layer][k-pair]
    half2v Wih[2][2][10];   // [gate][layer-1][k-pair]  (layers 1,2 only)
    float wx0[2];           // layer-0 input weight (IN=1)
    float bias[2][3];       // b_ih + b_hh folded
    float c[3] = {0.0f, 0.0f, 0.0f};  // cell state, meaningful on half==1 lanes

    if (active) {
        const float* whh_l[3] = {whh0, whh1, whh2};
        const float* wih_l[3] = {wih0, wih1, wih2};
        const float* bih_l[3] = {bih0, bih1, bih2};
        const float* bhh_l[3] = {bhh0, bhh1, bhh2};
        const int rows[2] = {r0, r1};
#pragma unroll
        for (int g = 0; g < 2; ++g) {
            const int r = rows[g];
            wx0[g] = wih0[r];  // w_ih0 is (80,1)
#pragma unroll
            for (int l = 0; l < 3; ++l) {
                const float* W = whh_l[l] + r * HID;
#pragma unroll
                for (int k4 = 0; k4 < 5; ++k4) {
                    float4 v = *(const float4*)(W + 4 * k4);
                    Whh[g][l][2 * k4]     = pack2(v.x, v.y);
                    Whh[g][l][2 * k4 + 1] = pack2(v.z, v.w);
                }
                bias[g][l] = bih_l[l][r] + bhh_l[l][r];
            }
#pragma unroll
            for (int l = 1; l < 3; ++l) {
                const float* W = wih_l[l] + r * HID;
#pragma unroll
                for (int k4 = 0; k4 < 5; ++k4) {
                    float4 v = *(const float4*)(W + 4 * k4);
                    Wih[g][l - 1][2 * k4]     = pack2(v.x, v.y);
                    Wih[g][l - 1][2 * k4 + 1] = pack2(v.z, v.w);
                }
            }
        }
    }

    const float* xb = x + (long)b * T_LEN;

    for (int t = 0; t < T_LEN; ++t) {
        const float xt = xb[t];  // wave-uniform scalar load (L1/K$ hot)

        // ---------------- layer 0 ----------------
        float p0, p1;
        {
            half2v hp[10];
            load_h20(&hbuf[0][0], hp);
            float a0 = 0.f, a1 = 0.f, b0 = 0.f, b1 = 0.f;
#pragma unroll
            for (int k = 0; k < 5; ++k) {
                a0 = fdot2_(Whh[0][0][k], hp[k], a0);
                b0 = fdot2_(Whh[1][0][k], hp[k], b0);
            }
#pragma unroll
            for (int k = 5; k < 10; ++k) {
                a1 = fdot2_(Whh[0][0][k], hp[k], a1);
                b1 = fdot2_(Whh[1][0][k], hp[k], b1);
            }
            p0 = bias[0][0] + wx0[0] * xt + a0 + a1;
            p1 = bias[1][0] + wx0[1] * xt + b0 + b1;
        }
        if (active && half == 0) {
            ubuf[j] = sigmoid_f(p0) * tanh_f(p1);  // sigma(i)*tanh(g)
        }
        __syncthreads();
        if (active && half == 1) {
            float cn = sigmoid_f(p0) * c[0] + ubuf[j];  // sigma(f)*c + u
            c[0] = cn;
            float hn = sigmoid_f(p1) * tanh_f(cn);      // sigma(o)*tanh(c)
            hbuf[0][j] = (_Float16)hn;
        }
        __syncthreads();

        // ---------------- layers 1, 2 ----------------
#pragma unroll
        for (int l = 1; l < 3; ++l) {
            float q0, q1;
            {
                half2v hp[10], xv[10];
                load_h20(&hbuf[l][0], hp);       // own h (t-1)
                load_h20(&hbuf[l - 1][0], xv);   // layer below's h (t)
                float a0 = 0.f, a1 = 0.f, b0 = 0.f, b1 = 0.f;
                float a2 = 0.f, a3 = 0.f, b2 = 0.f, b3 = 0.f;
#pragma unroll
                for (int k = 0; k < 5; ++k) {
                    a0 = fdot2_(Whh[0][l][k], hp[k], a0);
                    b0 = fdot2_(Whh[1][l][k], hp[k], b0);
                    a2 = fdot2_(Wih[0][l - 1][k], xv[k], a2);
                    b2 = fdot2_(Wih[1][l - 1][k], xv[k], b2);
                }
#pragma unroll
                for (int k = 5; k < 10; ++k) {
                    a1 = fdot2_(Whh[0][l][k], hp[k], a1);
                    b1 = fdot2_(Whh[1][l][k], hp[k], b1);
                    a3 = fdot2_(Wih[0][l - 1][k], xv[k], a3);
                    b3 = fdot2_(Wih[1][l - 1][k], xv[k], b3);
                }
                q0 = bias[0][l] + (a0 + a1) + (a2 + a3);
                q1 = bias[1][l] + (b0 + b1) + (b2 + b3);
            }
            if (active && half == 0) {
                ubuf[j] = sigmoid_f(q0) * tanh_f(q1);
            }
            __syncthreads();
            if (active && half == 1) {
                float cn = sigmoid_f(q0) * c[l] + ubuf[j];
                c[l] = cn;
                float hn = sigmoid_f(q1) * tanh_f(cn);
                hbuf[l][j] = (_Float16)hn;
            }
            __syncthreads();
        }
    }

    // FC epilogue: out[b][o] = fc_w[o][:] . h2 + fc_b[o]
    if (tid < 2) {
        float acc = fcb[tid];
#pragma unroll
        for (int k = 0; k < HID; ++k) {
            acc += fcw[tid * HID + k] * (float)hbuf[2][k];
        }
        out[b * 2 + tid] = acc;
    }
}

extern "C" void kernel_launch(void* const* d_in, const int* in_sizes, int n_in,
                              void* d_out, int out_size, void* d_ws, size_t ws_size,
                              hipStream_t stream) {
    const float* x    = (const float*)d_in[0];
    const float* wih0 = (const float*)d_in[1];
    const float* whh0 = (const float*)d_in[2];
    const float* bih0 = (const float*)d_in[3];
    const float* bhh0 = (const float*)d_in[4];
    const float* wih1 = (const float*)d_in[5];
    const float* whh1 = (const float*)d_in[6];
    const float* bih1 = (const float*)d_in[7];
    const float* bhh1 = (const float*)d_in[8];
    const float* wih2 = (const float*)d_in[9];
    const float* whh2 = (const float*)d_in[10];
    const float* bih2 = (const float*)d_in[11];
    const float* bhh2 = (const float*)d_in[12];
    const float* fcw  = (const float*)d_in[13];
    const float* fcb  = (const float*)d_in[14];

    lstm3_fused<<<dim3(NBATCH), dim3(64), 0, stream>>>(
        x, wih0, whh0, bih0, bhh0,
        wih1, whh1, bih1, bhh1,
        wih2, whh2, bih2, bhh2,
        fcw, fcb, (float*)d_out);
}

// Round 2
// 1038.572 us; speedup vs baseline: 1.2159x; 1.2159x over previous
//
#include <hip/hip_runtime.h>

typedef _Float16 half2v __attribute__((ext_vector_type(2)));

#define T_LEN 1024
#define NBATCH 1024
#define HID 20

#if defined(__has_builtin)
#if __has_builtin(__builtin_amdgcn_fdot2)
#define HAVE_FDOT2 1
#endif
#endif

__device__ __forceinline__ float fdot2_(half2v a, half2v b, float c) {
#ifdef HAVE_FDOT2
    return __builtin_amdgcn_fdot2(a, b, c, false);
#else
    return c + (float)a[0] * (float)b[0] + (float)a[1] * (float)b[1];
#endif
}

__device__ __forceinline__ half2v pack2(float a, float b) {
    half2v r;
    r[0] = (_Float16)a;
    r[1] = (_Float16)b;
    return r;
}

// tanh via sigmoid identity (used for tanh(c) on the update lanes)
__device__ __forceinline__ float tanh_s(float z) {
    return 2.0f / (1.0f + __expf(-2.0f * z)) - 1.0f;
}

// Load 20 f16 values (one padded 24-half row, 16B-aligned) into 10 half2 regs.
__device__ __forceinline__ void load_h20(const _Float16* row, half2v hp[10]) {
    uint4 q0 = *(const uint4*)(row);        // halfs 0..7
    uint4 q1 = *(const uint4*)(row + 8);    // halfs 8..15
    uint2 q2 = *(const uint2*)(row + 16);   // halfs 16..19
    hp[0] = __builtin_bit_cast(half2v, q0.x);
    hp[1] = __builtin_bit_cast(half2v, q0.y);
    hp[2] = __builtin_bit_cast(half2v, q0.z);
    hp[3] = __builtin_bit_cast(half2v, q0.w);
    hp[4] = __builtin_bit_cast(half2v, q1.x);
    hp[5] = __builtin_bit_cast(half2v, q1.y);
    hp[6] = __builtin_bit_cast(half2v, q1.z);
    hp[7] = __builtin_bit_cast(half2v, q1.w);
    hp[8] = __builtin_bit_cast(half2v, q2.x);
    hp[9] = __builtin_bit_cast(half2v, q2.y);
}

// Two waves per batch element (128-thread block), 1 gate per lane:
//   wave 0: lanes 0..19 -> i(j), lanes 20..39 -> g(j)   [tanh lanes]
//   wave 1: lanes 0..19 -> f(j), lanes 20..39 -> o(j)
// Wave 0 lanes 0..19 own the c/h update for hidden unit j.
// Lanes 40..63 of each wave ride along on garbage, never write.
__global__ void __launch_bounds__(128) lstm3_fused2(
    const float* __restrict__ x,
    const float* __restrict__ wih0, const float* __restrict__ whh0,
    const float* __restrict__ bih0, const float* __restrict__ bhh0,
    const float* __restrict__ wih1, const float* __restrict__ whh1,
    const float* __restrict__ bih1, const float* __restrict__ bhh1,
    const float* __restrict__ wih2, const float* __restrict__ whh2,
    const float* __restrict__ bih2, const float* __restrict__ bhh2,
    const float* __restrict__ fcw, const float* __restrict__ fcb,
    float* __restrict__ out)
{
    __shared__ __align__(16) _Float16 hbuf[3][24];  // per-layer h, 48B padded rows
    __shared__ float fgo[40];                        // sigma(f) [0..19], sigma(o) [20..39]

    const int tid = threadIdx.x;
    const int wv = tid >> 6;     // 0: i/g, 1: f/o
    const int lane = tid & 63;
    const int b = blockIdx.x;

    // zero h state (h0 = c0 = 0)
    if (tid < 3 * 24) ((_Float16*)hbuf)[tid] = (_Float16)0.0f;
    __syncthreads();

    const int j = (lane < 40) ? (lane % 20) : 0;
    const bool hi = (lane >= 20) && (lane < 40);
    const bool upd = (wv == 0) && (lane < 20);   // update-owner lanes

    // gate row in the (80 x *) weight matrices; idle lanes clamp to row 0
    int r;
    if (wv == 0) r = hi ? (2 * HID + j) : j;            // g : i
    else         r = hi ? (3 * HID + j) : (HID + j);    // o : f

    // activation = kA / (1 + exp(kK*z)) + kB
    //   sigmoid: kK=-1, kA=1, kB=0 ;  tanh (g-lanes): kK=-2, kA=2, kB=-1
    const bool is_g = (wv == 0) && hi;
    const float kK = is_g ? -2.0f : -1.0f;
    const float kA = is_g ? 2.0f : 1.0f;
    const float kB = is_g ? -1.0f : 0.0f;

    half2v Whh[3][10];   // [layer][k-pair]
    half2v Wih[2][10];   // [layer-1][k-pair] (layers 1,2)
    float bias[3];
    float wx;
    {
        const float* whh_l[3] = {whh0, whh1, whh2};
        const float* wih_l[3] = {wih0, wih1, wih2};
        const float* bih_l[3] = {bih0, bih1, bih2};
        const float* bhh_l[3] = {bhh0, bhh1, bhh2};
        wx = wih0[r];  // w_ih0 is (80,1)
#pragma unroll
        for (int l = 0; l < 3; ++l) {
            const float* W = whh_l[l] + r * HID;
#pragma unroll
            for (int k4 = 0; k4 < 5; ++k4) {
                float4 v = *(const float4*)(W + 4 * k4);
                Whh[l][2 * k4]     = pack2(v.x, v.y);
                Whh[l][2 * k4 + 1] = pack2(v.z, v.w);
            }
            bias[l] = bih_l[l][r] + bhh_l[l][r];
        }
#pragma unroll
        for (int l = 1; l < 3; ++l) {
            const float* W = wih_l[l] + r * HID;
#pragma unroll
            for (int k4 = 0; k4 < 5; ++k4) {
                float4 v = *(const float4*)(W + 4 * k4);
                Wih[l - 1][2 * k4]     = pack2(v.x, v.y);
                Wih[l - 1][2 * k4 + 1] = pack2(v.z, v.w);
            }
        }
    }

    float c[3] = {0.0f, 0.0f, 0.0f};  // cell state, meaningful on upd lanes

    const float* xb = x + (long)b * T_LEN;

    for (int t = 0; t < T_LEN; ++t) {
        const float xt = xb[t];  // wave-uniform scalar load

        // ---- hoisted hh-dots for all 3 layers (3 independent ILP chains) ----
        float s0 = 0.f, s1 = 0.f, s2 = 0.f;
        {
            half2v hp0[10], hp1[10], hp2[10];
            load_h20(&hbuf[0][0], hp0);
            load_h20(&hbuf[1][0], hp1);
            load_h20(&hbuf[2][0], hp2);
#pragma unroll
            for (int k = 0; k < 10; ++k) {
                s0 = fdot2_(Whh[0][k], hp0[k], s0);
                s1 = fdot2_(Whh[1][k], hp1[k], s1);
                s2 = fdot2_(Whh[2][k], hp2[k], s2);
            }
        }

        // ---------------- layer 0 ----------------
        {
            float pre = s0 + bias[0] + wx * xt;
            float a = kA / (1.0f + __expf(kK * pre)) + kB;
            if (wv == 1 && lane < 40) fgo[lane] = a;         // sigma(f), sigma(o)
            float ag = __shfl(a, lane + 20, 64);             // tanh(g) for lanes<20
            float u = a * ag;                                // sigma(i)*tanh(g) on wv0
            __syncthreads();                                 // A0: fgo visible
            if (upd) {
                float sf = fgo[j], so = fgo[20 + j];
                float cn = sf * c[0] + u;
                c[0] = cn;
                hbuf[0][j] = (_Float16)(so * tanh_s(cn));
            }
            __syncthreads();                                 // B0: h0(t) visible
        }

        // ---------------- layers 1, 2 ----------------
#pragma unroll
        for (int l = 1; l < 3; ++l) {
            half2v xv[10];
            load_h20(&hbuf[l - 1][0], xv);                   // layer below's h(t)
            float p0 = (l == 1 ? s1 : s2) + bias[l];
            float p1 = 0.f;
#pragma unroll
            for (int k = 0; k < 5; ++k) {
                p0 = fdot2_(Wih[l - 1][k], xv[k], p0);
                p1 = fdot2_(Wih[l - 1][k + 5], xv[k + 5], p1);
            }
            float pre = p0 + p1;
            float a = kA / (1.0f + __expf(kK * pre)) + kB;
            if (wv == 1 && lane < 40) fgo[lane] = a;
            float ag = __shfl(a, lane + 20, 64);
            float u = a * ag;
            __syncthreads();                                 // A_l
            if (upd) {
                float sf = fgo[j], so = fgo[20 + j];
                float cn = sf * c[l] + u;
                c[l] = cn;
                hbuf[l][j] = (_Float16)(so * tanh_s(cn));
            }
            __syncthreads();                                 // B_l
        }
    }

    // FC epilogue: out[b][o] = fc_w[o][:] . h2 + fc_b[o]
    if (tid < 2) {
        float acc = fcb[tid];
#pragma unroll
        for (int k = 0; k < HID; ++k) {
            acc += fcw[tid * HID + k] * (float)hbuf[2][k];
        }
        out[b * 2 + tid] = acc;
    }
}

extern "C" void kernel_launch(void* const* d_in, const int* in_sizes, int n_in,
                              void* d_out, int out_size, void* d_ws, size_t ws_size,
                              hipStream_t stream) {
    const float* x    = (const float*)d_in[0];
    const float* wih0 = (const float*)d_in[1];
    const float* whh0 = (const float*)d_in[2];
    const float* bih0 = (const float*)d_in[3];
    const float* bhh0 = (const float*)d_in[4];
    const float* wih1 = (const float*)d_in[5];
    const float* whh1 = (const float*)d_in[6];
    const float* bih1 = (const float*)d_in[7];
    const float* bhh1 = (const float*)d_in[8];
    const float* wih2 = (const float*)d_in[9];
    const float* whh2 = (const float*)d_in[10];
    const float* bih2 = (const float*)d_in[11];
    const float* bhh2 = (const float*)d_in[12];
    const float* fcw  = (const float*)d_in[13];
    const float* fcb  = (const float*)d_in[14];

    lstm3_fused2<<<dim3(NBATCH), dim3(128), 0, stream>>>(
        x, wih0, whh0, bih0, bhh0,
        wih1, whh1, bih1, bhh1,
        wih2, whh2, bih2, bhh2,
        fcw, fcb, (float*)d_out);
}

// Round 3
// 1028.262 us; speedup vs baseline: 1.2281x; 1.0100x over previous
//
#include <hip/hip_runtime.h>

typedef _Float16 half2v __attribute__((ext_vector_type(2)));

#define T_LEN 1024
#define NBATCH 1024
#define HID 20

#if defined(__has_builtin)
#if __has_builtin(__builtin_amdgcn_fdot2)
#define HAVE_FDOT2 1
#endif
#endif

__device__ __forceinline__ float fdot2_(half2v a, half2v b, float c) {
#ifdef HAVE_FDOT2
    return __builtin_amdgcn_fdot2(a, b, c, false);
#else
    return c + (float)a[0] * (float)b[0] + (float)a[1] * (float)b[1];
#endif
}

__device__ __forceinline__ half2v pack2(float a, float b) {
    half2v r;
    r[0] = (_Float16)a;
    r[1] = (_Float16)b;
    return r;
}

// tanh via sigmoid identity
__device__ __forceinline__ float tanh_s(float z) {
    return 2.0f / (1.0f + __expf(-2.0f * z)) - 1.0f;
}

// Load 20 f16 values (one padded 24-half, 48B row, 16B-aligned) into 10 half2.
__device__ __forceinline__ void load_h20(const _Float16* row, half2v hp[10]) {
    uint4 q0 = *(const uint4*)(row);        // halfs 0..7
    uint4 q1 = *(const uint4*)(row + 8);    // halfs 8..15
    uint2 q2 = *(const uint2*)(row + 16);   // halfs 16..19
    hp[0] = __builtin_bit_cast(half2v, q0.x);
    hp[1] = __builtin_bit_cast(half2v, q0.y);
    hp[2] = __builtin_bit_cast(half2v, q0.z);
    hp[3] = __builtin_bit_cast(half2v, q0.w);
    hp[4] = __builtin_bit_cast(half2v, q1.x);
    hp[5] = __builtin_bit_cast(half2v, q1.y);
    hp[6] = __builtin_bit_cast(half2v, q1.z);
    hp[7] = __builtin_bit_cast(half2v, q1.w);
    hp[8] = __builtin_bit_cast(half2v, q2.x);
    hp[9] = __builtin_bit_cast(half2v, q2.y);
}

// Layer-pipelined 3-wave block (192 threads), one block per batch element.
// Wave l owns layer l; at iteration s it processes timestep t = s - l.
// Within a wave: lane j (0..19) -> gates i(j), g(j); lane 20+j -> f(j), o(j);
// lanes 40..63 ride along, never write. Gate exchange via one __shfl.
// h handoff between waves via double-buffered LDS rings, 1 barrier/iteration.
__global__ void __launch_bounds__(192) lstm3_pipe(
    const float* __restrict__ x,
    const float* __restrict__ wih0, const float* __restrict__ whh0,
    const float* __restrict__ bih0, const float* __restrict__ bhh0,
    const float* __restrict__ wih1, const float* __restrict__ whh1,
    const float* __restrict__ bih1, const float* __restrict__ bhh1,
    const float* __restrict__ wih2, const float* __restrict__ whh2,
    const float* __restrict__ bih2, const float* __restrict__ bhh2,
    const float* __restrict__ fcw, const float* __restrict__ fcb,
    float* __restrict__ out)
{
    // rings[l][parity][j]: h_l(t) lives in rings[l][t&1]
    __shared__ __align__(16) _Float16 rings[3][2][24];
    __shared__ float hfinal[HID];

    const int tid = threadIdx.x;
    const int wv = tid / 64;     // layer index
    const int lane = tid & 63;
    const int b = blockIdx.x;

    // zero all ring slots (h = 0 at t = -1)
    if (tid < 3 * 2 * 24) ((_Float16*)rings)[tid] = (_Float16)0.0f;
    __syncthreads();

    const int j = (lane < 40) ? (lane % 20) : 0;
    const bool low = lane < 20;                     // (i,g) lanes vs (f,o) lanes
    const int r0 = low ? j : (HID + j);             // i-row or f-row
    const int r1 = low ? (2 * HID + j) : (3 * HID + j);  // g-row or o-row

    // gate1 activation: tanh for g-lanes (low), sigmoid for o-lanes (high)
    const float kK = low ? -2.0f : -1.0f;
    const float kA = low ? 2.0f : 1.0f;
    const float kB = low ? -1.0f : 0.0f;

    const float* whh = (wv == 0) ? whh0 : (wv == 1) ? whh1 : whh2;
    const float* wih = (wv == 0) ? wih0 : (wv == 1) ? wih1 : wih2;
    const float* bih = (wv == 0) ? bih0 : (wv == 1) ? bih1 : bih2;
    const float* bhh = (wv == 0) ? bhh0 : (wv == 1) ? bhh1 : bhh2;

    half2v Whh[2][10];   // [gate][k-pair] recurrent weights
    half2v Wih[2][10];   // [gate][k-pair] input weights (waves 1,2)
    float wx0 = 0.0f, wx1 = 0.0f;  // wave 0: scalar input weights (IN=1)
    float bias0, bias1;
    {
#pragma unroll
        for (int k4 = 0; k4 < 5; ++k4) {
            float4 v0 = *(const float4*)(whh + r0 * HID + 4 * k4);
            Whh[0][2 * k4]     = pack2(v0.x, v0.y);
            Whh[0][2 * k4 + 1] = pack2(v0.z, v0.w);
            float4 v1 = *(const float4*)(whh + r1 * HID + 4 * k4);
            Whh[1][2 * k4]     = pack2(v1.x, v1.y);
            Whh[1][2 * k4 + 1] = pack2(v1.z, v1.w);
        }
        bias0 = bih[r0] + bhh[r0];
        bias1 = bih[r1] + bhh[r1];
        if (wv == 0) {
            wx0 = wih[r0];  // w_ih0 is (80,1)
            wx1 = wih[r1];
        } else {
#pragma unroll
            for (int k4 = 0; k4 < 5; ++k4) {
                float4 v0 = *(const float4*)(wih + r0 * HID + 4 * k4);
                Wih[0][2 * k4]     = pack2(v0.x, v0.y);
                Wih[0][2 * k4 + 1] = pack2(v0.z, v0.w);
                float4 v1 = *(const float4*)(wih + r1 * HID + 4 * k4);
                Wih[1][2 * k4]     = pack2(v1.x, v1.y);
                Wih[1][2 * k4 + 1] = pack2(v1.z, v1.w);
            }
        }
    }

    float c = 0.0f;  // cell state (meaningful on lanes 20..39)
    const float* xb = x + (long)b * T_LEN;
    const int srcl = low ? lane : (lane - 20);  // shfl source for u

    for (int s = 0; s < T_LEN + 2; ++s) {
        const int t = s - wv;
        if (t >= 0 && t < T_LEN) {
            float xt = 0.0f;
            if (wv == 0) xt = xb[t];  // wave-uniform scalar load, issued early

            half2v hown[10], hbel[10];
            load_h20(&rings[wv][(t + 1) & 1][0], hown);   // own h(t-1)
            if (wv > 0) load_h20(&rings[wv - 1][t & 1][0], hbel);  // below h(t)

            float d0 = 0.f, d1 = 0.f, g0 = 0.f, g1 = 0.f;
            float d2 = 0.f, d3 = 0.f, g2 = 0.f, g3 = 0.f;
#pragma unroll
            for (int k = 0; k < 5; ++k) {
                d0 = fdot2_(Whh[0][k],     hown[k],     d0);
                d1 = fdot2_(Whh[0][k + 5], hown[k + 5], d1);
                g0 = fdot2_(Whh[1][k],     hown[k],     g0);
                g1 = fdot2_(Whh[1][k + 5], hown[k + 5], g1);
            }
            if (wv > 0) {
#pragma unroll
                for (int k = 0; k < 5; ++k) {
                    d2 = fdot2_(Wih[0][k],     hbel[k],     d2);
                    d3 = fdot2_(Wih[0][k + 5], hbel[k + 5], d3);
                    g2 = fdot2_(Wih[1][k],     hbel[k],     g2);
                    g3 = fdot2_(Wih[1][k + 5], hbel[k + 5], g3);
                }
            }
            float pre0 = bias0 + (d0 + d1) + (d2 + d3);
            float pre1 = bias1 + (g0 + g1) + (g2 + g3);
            if (wv == 0) { pre0 += wx0 * xt; pre1 += wx1 * xt; }

            float a0 = 1.0f / (1.0f + __expf(-pre0));          // sigma(i) / sigma(f)
            float a1 = kA / (1.0f + __expf(kK * pre1)) + kB;   // tanh(g) / sigma(o)
            float u = a0 * a1;                                 // valid on low lanes
            float uf = __shfl(u, srcl, 64);                    // u to update lanes

            if (lane >= 20 && lane < 40) {
                float cn = a0 * c + uf;   // a0 = sigma(f)
                c = cn;
                float hn = a1 * tanh_s(cn);  // a1 = sigma(o)
                rings[wv][t & 1][j] = (_Float16)hn;
                if (wv == 2 && t == T_LEN - 1) hfinal[j] = hn;
            }
        }
        __syncthreads();  // publishes this iteration's h to the wave above
    }

    // FC epilogue: out[b][o] = fc_w[o][:] . h2(T-1) + fc_b[o]
    if (tid < 2) {
        float acc = fcb[tid];
#pragma unroll
        for (int k = 0; k < HID; ++k) {
            acc += fcw[tid * HID + k] * hfinal[k];
        }
        out[b * 2 + tid] = acc;
    }
}

extern "C" void kernel_launch(void* const* d_in, const int* in_sizes, int n_in,
                              void* d_out, int out_size, void* d_ws, size_t ws_size,
                              hipStream_t stream) {
    const float* x    = (const float*)d_in[0];
    const float* wih0 = (const float*)d_in[1];
    const float* whh0 = (const float*)d_in[2];
    const float* bih0 = (const float*)d_in[3];
    const float* bhh0 = (const float*)d_in[4];
    const float* wih1 = (const float*)d_in[5];
    const float* whh1 = (const float*)d_in[6];
    const float* bih1 = (const float*)d_in[7];
    const float* bhh1 = (const float*)d_in[8];
    const float* wih2 = (const float*)d_in[9];
    const float* whh2 = (const float*)d_in[10];
    const float* bih2 = (const float*)d_in[11];
    const float* bhh2 = (const float*)d_in[12];
    const float* fcw  = (const float*)d_in[13];
    const float* fcb  = (const float*)d_in[14];

    lstm3_pipe<<<dim3(NBATCH), dim3(192), 0, stream>>>(
        x, wih0, whh0, bih0, bhh0,
        wih1, whh1, bih1, bhh1,
        wih2, whh2, bih2, bhh2,
        fcw, fcb, (float*)d_out);
}

// Round 4
// 999.360 us; speedup vs baseline: 1.2636x; 1.0289x over previous
//
#include <hip/hip_runtime.h>

typedef _Float16 half2v __attribute__((ext_vector_type(2)));

#define T_LEN 1024
#define NBATCH 1024
#define HID 20

#if defined(__has_builtin)
#if __has_builtin(__builtin_amdgcn_fdot2)
#define HAVE_FDOT2 1
#endif
#endif

__device__ __forceinline__ float fdot2_(half2v a, half2v b, float c) {
#ifdef HAVE_FDOT2
    return __builtin_amdgcn_fdot2(a, b, c, false);
#else
    return c + (float)a[0] * (float)b[0] + (float)a[1] * (float)b[1];
#endif
}

__device__ __forceinline__ half2v pack2(float a, float b) {
    half2v r;
    r[0] = (_Float16)a;
    r[1] = (_Float16)b;
    return r;
}

// tanh via sigmoid identity
__device__ __forceinline__ float tanh_s(float z) {
    return 2.0f / (1.0f + __expf(-2.0f * z)) - 1.0f;
}

// Load 20 f16 values (one padded 24-half, 48B row, 16B-aligned) into 10 half2.
__device__ __forceinline__ void load_h20(const _Float16* row, half2v hp[10]) {
    uint4 q0 = *(const uint4*)(row);        // halfs 0..7
    uint4 q1 = *(const uint4*)(row + 8);    // halfs 8..15
    uint2 q2 = *(const uint2*)(row + 16);   // halfs 16..19
    hp[0] = __builtin_bit_cast(half2v, q0.x);
    hp[1] = __builtin_bit_cast(half2v, q0.y);
    hp[2] = __builtin_bit_cast(half2v, q0.z);
    hp[3] = __builtin_bit_cast(half2v, q0.w);
    hp[4] = __builtin_bit_cast(half2v, q1.x);
    hp[5] = __builtin_bit_cast(half2v, q1.y);
    hp[6] = __builtin_bit_cast(half2v, q1.z);
    hp[7] = __builtin_bit_cast(half2v, q1.w);
    hp[8] = __builtin_bit_cast(half2v, q2.x);
    hp[9] = __builtin_bit_cast(half2v, q2.y);
}

// Layer-pipelined 3-wave block (192 threads), one block per batch element.
// Wave l owns layer l; at iteration s it processes timestep t = s - l.
// Lanes 0..19 -> gates i(j), g(j); lanes 20..39 -> f(j), o(j); 40..63 idle.
// x staged in LDS once; ring pointers precomputed (loop unrolled x2 over parity).
__global__ void __launch_bounds__(192, 3) lstm3_pipe2(
    const float* __restrict__ x,
    const float* __restrict__ wih0, const float* __restrict__ whh0,
    const float* __restrict__ bih0, const float* __restrict__ bhh0,
    const float* __restrict__ wih1, const float* __restrict__ whh1,
    const float* __restrict__ bih1, const float* __restrict__ bhh1,
    const float* __restrict__ wih2, const float* __restrict__ whh2,
    const float* __restrict__ bih2, const float* __restrict__ bhh2,
    const float* __restrict__ fcw, const float* __restrict__ fcb,
    float* __restrict__ out)
{
    __shared__ __align__(16) float xlds[T_LEN];           // 4 KB staged input
    __shared__ __align__(16) _Float16 rings[3][2][24];    // h double-buffer rings

    const int tid = threadIdx.x;
    const int wv = tid / 64;     // layer index
    const int lane = tid & 63;
    const int b = blockIdx.x;

    // stage x (coalesced float4) + zero rings
    {
        const float4* x4 = (const float4*)(x + (long)b * T_LEN);
        float4* xl4 = (float4*)xlds;
        for (int i = tid; i < T_LEN / 4; i += 192) xl4[i] = x4[i];
        if (tid < 3 * 2 * 24) ((_Float16*)rings)[tid] = (_Float16)0.0f;
    }

    const int j = (lane < 40) ? (lane % 20) : 0;
    const bool low = lane < 20;                          // (i,g) lanes
    const int r0 = low ? j : (HID + j);                  // i-row or f-row
    const int r1 = low ? (2 * HID + j) : (3 * HID + j);  // g-row or o-row
    const int srcl = low ? lane : (lane - 20);           // shfl source for u

    // gate1 activation: tanh on g-lanes (low), sigmoid on o-lanes (high)
    const float kK = low ? -2.0f : -1.0f;
    const float kA = low ? 2.0f : 1.0f;
    const float kB = low ? -1.0f : 0.0f;

    const float* whh = (wv == 0) ? whh0 : (wv == 1) ? whh1 : whh2;
    const float* wih = (wv == 0) ? wih0 : (wv == 1) ? wih1 : wih2;
    const float* bih = (wv == 0) ? bih0 : (wv == 1) ? bih1 : bih2;
    const float* bhh = (wv == 0) ? bhh0 : (wv == 1) ? bhh1 : bhh2;

    half2v Whh[2][10];
    half2v Wih[2][10];
    float wx0 = 0.0f, wx1 = 0.0f;
    float bias0, bias1;
    {
#pragma unroll
        for (int k4 = 0; k4 < 5; ++k4) {
            float4 v0 = *(const float4*)(whh + r0 * HID + 4 * k4);
            Whh[0][2 * k4]     = pack2(v0.x, v0.y);
            Whh[0][2 * k4 + 1] = pack2(v0.z, v0.w);
            float4 v1 = *(const float4*)(whh + r1 * HID + 4 * k4);
            Whh[1][2 * k4]     = pack2(v1.x, v1.y);
            Whh[1][2 * k4 + 1] = pack2(v1.z, v1.w);
        }
        bias0 = bih[r0] + bhh[r0];
        bias1 = bih[r1] + bhh[r1];
        if (wv == 0) {
            wx0 = wih[r0];  // w_ih0 is (80,1)
            wx1 = wih[r1];
        } else {
#pragma unroll
            for (int k4 = 0; k4 < 5; ++k4) {
                float4 v0 = *(const float4*)(wih + r0 * HID + 4 * k4);
                Wih[0][2 * k4]     = pack2(v0.x, v0.y);
                Wih[0][2 * k4 + 1] = pack2(v0.z, v0.w);
                float4 v1 = *(const float4*)(wih + r1 * HID + 4 * k4);
                Wih[1][2 * k4]     = pack2(v1.x, v1.y);
                Wih[1][2 * k4 + 1] = pack2(v1.z, v1.w);
            }
        }
    }

    // Precomputed ring pointers.
    //   own-read parity  (t+1)&1 : s even -> (1-wv)&1
    //   below-read parity (t)&1  : s even -> wv&1
    //   write parity      (t)&1  : s even -> wv&1
    const int po_e = (1 - wv) & 1;
    const int pb_e = wv & 1;
    const _Float16* ro_e = &rings[wv][po_e][0];
    const _Float16* ro_o = &rings[wv][po_e ^ 1][0];
    const _Float16* rb_e = (wv > 0) ? &rings[wv - 1][pb_e][0] : &rings[0][0][0];
    const _Float16* rb_o = (wv > 0) ? &rings[wv - 1][pb_e ^ 1][0] : &rings[0][1][0];
    _Float16* wp_e = &rings[wv][pb_e][0];
    _Float16* wp_o = &rings[wv][pb_e ^ 1][0];

    float c = 0.0f;  // cell state (lanes 20..39)

    __syncthreads();  // x + rings visible

    auto body = [&](int t, const _Float16* rown, const _Float16* rbel,
                    _Float16* wp) {
        if (t < 0 || t >= T_LEN) return;  // wave-uniform
        half2v hown[10];
        load_h20(rown, hown);
        float d0 = 0.f, d1 = 0.f, g0 = 0.f, g1 = 0.f;
        float d2 = 0.f, d3 = 0.f, g2 = 0.f, g3 = 0.f;
        float xt = 0.0f;
        if (wv == 0) {
            xt = xlds[t];
#pragma unroll
            for (int k = 0; k < 5; ++k) {
                d0 = fdot2_(Whh[0][k],     hown[k],     d0);
                d1 = fdot2_(Whh[0][k + 5], hown[k + 5], d1);
                g0 = fdot2_(Whh[1][k],     hown[k],     g0);
                g1 = fdot2_(Whh[1][k + 5], hown[k + 5], g1);
            }
        } else {
            half2v hbel[10];
            load_h20(rbel, hbel);
#pragma unroll
            for (int k = 0; k < 5; ++k) {
                d0 = fdot2_(Whh[0][k],     hown[k],     d0);
                d1 = fdot2_(Whh[0][k + 5], hown[k + 5], d1);
                g0 = fdot2_(Whh[1][k],     hown[k],     g0);
                g1 = fdot2_(Whh[1][k + 5], hown[k + 5], g1);
                d2 = fdot2_(Wih[0][k],     hbel[k],     d2);
                d3 = fdot2_(Wih[0][k + 5], hbel[k + 5], d3);
                g2 = fdot2_(Wih[1][k],     hbel[k],     g2);
                g3 = fdot2_(Wih[1][k + 5], hbel[k + 5], g3);
            }
        }
        float pre0 = bias0 + (d0 + d1) + (d2 + d3);
        float pre1 = bias1 + (g0 + g1) + (g2 + g3);
        if (wv == 0) { pre0 += wx0 * xt; pre1 += wx1 * xt; }

        float a0 = 1.0f / (1.0f + __expf(-pre0));        // sigma(i)/sigma(f)
        float a1 = kA / (1.0f + __expf(kK * pre1)) + kB; // tanh(g)/sigma(o)
        float u = a0 * a1;
        float uf = __shfl(u, srcl, 64);
        if (lane >= 20 && lane < 40) {
            float cn = a0 * c + uf;      // a0 = sigma(f)
            c = cn;
            wp[j] = (_Float16)(a1 * tanh_s(cn));  // a1 = sigma(o)
        }
    };

    for (int s = 0; s < T_LEN + 2; s += 2) {
        body(s - wv,     ro_e, rb_e, wp_e);
        __syncthreads();
        body(s + 1 - wv, ro_o, rb_o, wp_o);
        __syncthreads();
    }

    // FC epilogue: h2(T-1) sits in rings[2][(T_LEN-1)&1] = rings[2][1]
    if (tid < 2) {
        float acc = fcb[tid];
        const _Float16* h2 = &rings[2][1][0];
#pragma unroll
        for (int k = 0; k < HID; ++k) {
            acc += fcw[tid * HID + k] * (float)h2[k];
        }
        out[b * 2 + tid] = acc;
    }
}

extern "C" void kernel_launch(void* const* d_in, const int* in_sizes, int n_in,
                              void* d_out, int out_size, void* d_ws, size_t ws_size,
                              hipStream_t stream) {
    const float* x    = (const float*)d_in[0];
    const float* wih0 = (const float*)d_in[1];
    const float* whh0 = (const float*)d_in[2];
    const float* bih0 = (const float*)d_in[3];
    const float* bhh0 = (const float*)d_in[4];
    const float* wih1 = (const float*)d_in[5];
    const float* whh1 = (const float*)d_in[6];
    const float* bih1 = (const float*)d_in[7];
    const float* bhh1 = (const float*)d_in[8];
    const float* wih2 = (const float*)d_in[9];
    const float* whh2 = (const float*)d_in[10];
    const float* bih2 = (const float*)d_in[11];
    const float* bhh2 = (const float*)d_in[12];
    const float* fcw  = (const float*)d_in[13];
    const float* fcb  = (const float*)d_in[14];

    lstm3_pipe2<<<dim3(NBATCH), dim3(192), 0, stream>>>(
        x, wih0, whh0, bih0, bhh0,
        wih1, whh1, bih1, bhh1,
        wih2, whh2, bih2, bhh2,
        fcw, fcb, (float*)d_out);
}